// Round 18
// baseline (502.308 us; speedup 1.0000x reference)
//
#include <hip/hip_runtime.h>

#define NNODE 10000
#define NEDGE 160000
#define DD 256

using f32x4  = __attribute__((ext_vector_type(4))) float;
using bf16x8 = __attribute__((ext_vector_type(8))) short;
using u32x4  = __attribute__((ext_vector_type(4))) unsigned;

__device__ inline short f2bf(float f) {
  unsigned u = __float_as_uint(f);
  unsigned r = (u + 0x7fffu + ((u >> 16) & 1u)) >> 16;
  return (short)(unsigned short)r;
}

__device__ inline float bf2f(short s) {
  return __uint_as_float(((unsigned)(unsigned short)s) << 16);
}

__device__ inline unsigned pkbf(float a, float b) {
  unsigned r;
  asm("v_cvt_pk_bf16_f32 %0, %1, %2" : "=v"(r) : "v"(a), "v"(b));
  return r;
}

// bijective chunked XCD swizzle (8 XCDs) [m204]; measured neutral, kept (zero cost)
__device__ inline int xcd_chunked(int bid, int nwg) {
  const int NX = 8;
  int q = nwg / NX, r = nwg % NX;
  int x = bid % NX, pos = bid / NX;
  return (x < r) ? x * (q + 1) + pos : r * (q + 1) + (x - r) * q + pos;
}

__global__ void cast_x_kernel(const float* __restrict__ x, short* __restrict__ xb, int total) {
  int i = blockIdx.x * 256 + threadIdx.x;
  if (i < total) xb[i] = f2bf(x[i]);
}

// generic pack w[K][N] (f32) -> p[(k>>3)][n][k&7] (bf16)
__global__ void pack_w_kernel(const float* __restrict__ w, short* __restrict__ p, int K, int N) {
  int idx = blockIdx.x * 256 + threadIdx.x;
  if (idx >= K * N) return;
  int k = idx / N, n = idx - k * N;
  p[(size_t)(k >> 3) * N * 8 + (size_t)n * 8 + (k & 7)] = f2bf(w[idx]);
}

// e_w1 [768][512] split: rows 0..255 -> w1abp half0, 256..511 -> w1abp half1 (N=1024),
// rows 512..767 -> w1cp (N=512). Same MFMA-native (k>>3, n, k&7) layout.
__global__ void pack_ew1_kernel(const float* __restrict__ w, short* __restrict__ w1abp,
                                short* __restrict__ w1cp) {
  int idx = blockIdx.x * 256 + threadIdx.x;
  if (idx >= 768 * 512) return;
  int k = idx >> 9, n = idx & 511;
  short v = f2bf(w[idx]);
  if (k < 256) {
    w1abp[(size_t)(k >> 3) * 1024 * 8 + (size_t)n * 8 + (k & 7)] = v;
  } else if (k < 512) {
    int kk = k - 256;
    w1abp[(size_t)(kk >> 3) * 1024 * 8 + (size_t)(512 + n) * 8 + (kk & 7)] = v;
  } else {
    int kk = k - 512;
    w1cp[(size_t)(kk >> 3) * 512 * 8 + (size_t)n * 8 + (kk & 7)] = v;
  }
}

// ---------------- CSR build ----------------
__global__ void hist_kernel(const int* __restrict__ ei, int* __restrict__ deg) {
  int e = blockIdx.x * 256 + threadIdx.x;
  if (e < NEDGE) {
    int j = ei[NEDGE + e]; j = min(max(j, 0), NNODE - 1);
    atomicAdd(&deg[j], 1);
  }
}

__global__ void scan_kernel(const int* __restrict__ deg, int* __restrict__ row_start) {
  __shared__ int part[256];
  int t = threadIdx.x;
  const int CH = 40;
  int base = t * CH;
  int s = 0;
  for (int i = 0; i < CH; i++) {
    int idx = base + i;
    s += (idx < NNODE) ? deg[idx] : 0;
  }
  part[t] = s;
  __syncthreads();
  for (int off = 1; off < 256; off <<= 1) {
    int v = (t >= off) ? part[t - off] : 0;
    __syncthreads();
    part[t] += v;
    __syncthreads();
  }
  int run = (t == 0) ? 0 : part[t - 1];
  for (int i = 0; i < CH; i++) {
    int idx = base + i;
    if (idx < NNODE) { row_start[idx] = run; run += deg[idx]; }
  }
  if (t == 255) row_start[NNODE] = part[255];
}

__global__ void scatter_kernel(const int* __restrict__ ei, const int* __restrict__ row_start,
                               int* __restrict__ cursor, int* __restrict__ csr) {
  int e = blockIdx.x * 256 + threadIdx.x;
  if (e < NEDGE) {
    int j = ei[NEDGE + e]; j = min(max(j, 0), NNODE - 1);
    int p = atomicAdd(&cursor[j], 1);
    csr[row_start[j] + p] = e;
  }
}

// ---------------- precomp: Pab = x @ [W1a | W1b], packed-fragment bf16 ----------------
__global__ __launch_bounds__(256, 2)
void precomp_pab(const short* __restrict__ xb, const short* __restrict__ w1abp,
                 short* __restrict__ pab) {
  __shared__ __align__(16) short abuf[2048 * 8];  // 32 KB swizzled

  const int tid  = threadIdx.x;
  const int lane = tid & 63;
  const int wid  = tid >> 6;
  const int lhi  = lane >> 4;
  const int llo  = lane & 15;
  const int swz  = llo & 7;
  const int m0   = blockIdx.x * 64;
  const int h    = blockIdx.y;

  #pragma unroll
  for (int q = 0; q < 8; q++) {
    int S = wid * 512 + q * 64 + lane;
    int row = S >> 5;
    int segp = S & 31;
    int seg = segp ^ (row & 7);
    int rowg = min(m0 + row, NNODE - 1);
    __builtin_amdgcn_global_load_lds(
        (const int*)((const char*)xb + (size_t)rowg * 512 + seg * 16),
        (int*)(abuf + (size_t)(wid * 512 + q * 64) * 8), 16, 0, 0);
  }
  __syncthreads();

  f32x4 acc1[4][8] = {};
  const bf16x8* bp1 = (const bf16x8*)w1abp;
  #pragma unroll
  for (int kk = 0; kk < 256; kk += 32) {
    const int ks = kk >> 3;
    bf16x8 a[4];
    #pragma unroll
    for (int mf = 0; mf < 4; mf++)
      a[mf] = *(const bf16x8*)(abuf + ((mf * 16 + llo) * 32 + ((ks + lhi) ^ swz)) * 8);
    const bf16x8* bb = bp1 + (size_t)(ks + lhi) * 1024 + h * 512 + wid * 128 + llo;
    #pragma unroll
    for (int nf = 0; nf < 8; nf++) {
      bf16x8 b = bb[nf * 16];
      #pragma unroll
      for (int mf = 0; mf < 4; mf++)
        acc1[mf][nf] = __builtin_amdgcn_mfma_f32_16x16x32_bf16(a[mf], b, acc1[mf][nf], 0, 0, 0);
    }
  }

  #pragma unroll
  for (int mf = 0; mf < 4; mf++) {
    #pragma unroll
    for (int r = 0; r < 4; r++) {
      int row = m0 + mf * 16 + lhi * 4 + r;
      if (row < NNODE) {
        u32x4 wv = { pkbf(acc1[mf][0][r], acc1[mf][1][r]),
                     pkbf(acc1[mf][2][r], acc1[mf][3][r]),
                     pkbf(acc1[mf][4][r], acc1[mf][5][r]),
                     pkbf(acc1[mf][6][r], acc1[mf][7][r]) };
        *(u32x4*)(pab + (size_t)row * 1024 + h * 512 + llo * 32 + wid * 8) = wv;
      }
    }
  }
}

// ---------------- edge kernel (CSR-ordered, fused agg, pab[i]+pab[j] early prefetch) ----------------
__global__ __launch_bounds__(256, 2)
void fused_edge(const int* __restrict__ ei,
                const int* __restrict__ csr,
                const float* __restrict__ ea,
                const short* __restrict__ pab,
                const short* __restrict__ w1cp,
                const float* __restrict__ b1,
                const short* __restrict__ w2p,
                const float* __restrict__ b2,
                const float* __restrict__ gam,
                const float* __restrict__ bet,
                float* __restrict__ out,
                float* __restrict__ aggf)
{
  // union region: abufE (32KB stage) -> hid (64KB bf16) -> outt (66.56KB f32)
  __shared__ __align__(16) char smem[66560];
  __shared__ int eidx[64], idxi[64], idxj[64];
  __shared__ float pS[256], pQ[256];

  short* abufE = (short*)smem;  // [64][32 segs of 8] bf16 (ea), swizzled
  short* hid   = (short*)smem;  // [64][512] bf16, XOR-swizzled
  float* outt  = (float*)smem;  // [64][260] f32

  const int tid  = threadIdx.x;
  const int lane = tid & 63;
  const int wid  = tid >> 6;
  const int lhi  = lane >> 4;
  const int llo  = lane & 15;
  const int swz  = llo & 7;
  const int m0   = xcd_chunked(blockIdx.x, gridDim.x) * 64;
  const int bcol2 = wid * 64 + llo;

  if (tid < 64) {
    int e = csr[m0 + tid];
    eidx[tid] = e;
    int a = ei[e];
    int b = ei[NEDGE + e];
    idxi[tid] = min(max(a, 0), NNODE - 1);
    idxj[tid] = min(max(b, 0), NNODE - 1);
  }
  __syncthreads();

  // EARLY PREFETCH pab[i] (L3 random) and pab[j] (L2 CSR-local) into regs:
  // issued before ea staging so their latency hides under the nt-loads + cvt
  // VALU work AND GEMM_c. [R16 proved -24us for the i-side alone]
  bf16x8 paR[4][4], pbR[4][4];
  #pragma unroll
  for (int mf = 0; mf < 4; mf++) {
    #pragma unroll
    for (int r = 0; r < 4; r++) {
      int row = mf * 16 + lhi * 4 + r;
      paR[mf][r] = *(const bf16x8*)(pab + (size_t)idxi[row] * 1024 + llo * 32 + wid * 8);
      pbR[mf][r] = *(const bf16x8*)(pab + (size_t)idxj[row] * 1024 + 512 + llo * 32 + wid * 8);
    }
  }

  // stage ea tile (64 gathered rows, f32 -> bf16, swizzled); rows read ONCE -> nt
  #pragma unroll
  for (int q = 0; q < 8; q++) {
    int S = q * 256 + tid;
    int row = S >> 5;
    int segp = S & 31;
    int seg = segp ^ (row & 7);
    const f32x4* src = (const f32x4*)(ea + (size_t)eidx[row] * 256 + seg * 8);
    f32x4 u0 = __builtin_nontemporal_load(src);
    f32x4 u1 = __builtin_nontemporal_load(src + 1);
    u32x4 qv = { pkbf(u0.x, u0.y), pkbf(u0.z, u0.w), pkbf(u1.x, u1.y), pkbf(u1.z, u1.w) };
    *(u32x4*)(abufE + (size_t)S * 8) = qv;
  }
  __syncthreads();

  // ---------------- GEMM_c: [64 x 256] @ [256 x 512] ----------------
  f32x4 acc1[4][8] = {};
  const bf16x8* bp1 = (const bf16x8*)w1cp;
  #pragma unroll
  for (int kk = 0; kk < 256; kk += 32) {
    const int ks = kk >> 3;
    bf16x8 a[4];
    #pragma unroll
    for (int mf = 0; mf < 4; mf++)
      a[mf] = *(const bf16x8*)(abufE + ((mf * 16 + llo) * 32 + ((ks + lhi) ^ swz)) * 8);
    const bf16x8* bb = bp1 + (size_t)(ks + lhi) * 512 + wid * 128 + llo;
    #pragma unroll
    for (int nf = 0; nf < 8; nf++) {
      bf16x8 b = bb[nf * 16];
      #pragma unroll
      for (int mf = 0; mf < 4; mf++)
        acc1[mf][nf] = __builtin_amdgcn_mfma_f32_16x16x32_bf16(a[mf], b, acc1[mf][nf], 0, 0, 0);
    }
  }

  // add prefetched Pab[i] + Pab[j]
  #pragma unroll
  for (int mf = 0; mf < 4; mf++) {
    #pragma unroll
    for (int r = 0; r < 4; r++) {
      #pragma unroll
      for (int nf = 0; nf < 8; nf++)
        acc1[mf][nf][r] += bf2f(paR[mf][r][nf]) + bf2f(pbR[mf][r][nf]);
    }
  }

  // snapshot this thread's residual (bf16 ea) from abufE before hid overwrites it
  float resv[4][4][4];
  #pragma unroll
  for (int mf = 0; mf < 4; mf++) {
    #pragma unroll
    for (int r = 0; r < 4; r++) {
      int row = mf * 16 + lhi * 4 + r;
      #pragma unroll
      for (int nf = 0; nf < 4; nf++) {
        int col = bcol2 + nf * 16;
        resv[mf][r][nf] = bf2f(abufE[row * 256 + (((col >> 3) ^ (row & 7)) << 3) + (col & 7)]);
      }
    }
  }
  __syncthreads();  // all abufE reads done before hid overwrites it

  // ---------------- bias + relu -> hid (XOR-swizzled, K=512) ----------------
  #pragma unroll
  for (int nf = 0; nf < 8; nf++) {
    int col = wid * 128 + nf * 16 + llo;
    float bb = b1[col];
    int cs = col >> 3, cl = col & 7;
    #pragma unroll
    for (int mf = 0; mf < 4; mf++) {
      #pragma unroll
      for (int r = 0; r < 4; r++) {
        int row = mf * 16 + lhi * 4 + r;
        float v = acc1[mf][nf][r] + bb;
        v = v > 0.f ? v : 0.f;
        hid[row * 512 + ((cs ^ (row & 7)) * 8) + cl] = f2bf(v);
      }
    }
  }
  __syncthreads();

  // ---------------- GEMM2: [64 x 512] @ [512 x 256] ----------------
  f32x4 acc2[4][4] = {};
  const bf16x8* bp2 = (const bf16x8*)w2p;
  #pragma unroll
  for (int kk = 0; kk < 512; kk += 32) {
    const int ks = kk >> 3;
    bf16x8 a[4];
    #pragma unroll
    for (int mf = 0; mf < 4; mf++) {
      int row = mf * 16 + llo;
      a[mf] = *(const bf16x8*)(hid + row * 512 + (((ks + lhi) ^ swz) * 8));
    }
    const bf16x8* bb = bp2 + (size_t)(ks + lhi) * 256 + bcol2;
    #pragma unroll
    for (int nf = 0; nf < 4; nf++) {
      bf16x8 b = bb[nf * 16];
      #pragma unroll
      for (int mf = 0; mf < 4; mf++)
        acc2[mf][nf] = __builtin_amdgcn_mfma_f32_16x16x32_bf16(a[mf], b, acc2[mf][nf], 0, 0, 0);
    }
  }

  // ---------------- LayerNorm stats ----------------
  float bb2[4], gg[4], be[4];
  #pragma unroll
  for (int nf = 0; nf < 4; nf++) {
    int col = bcol2 + nf * 16;
    bb2[nf] = b2[col]; gg[nf] = gam[col]; be[nf] = bet[col];
  }
  #pragma unroll
  for (int mf = 0; mf < 4; mf++)
    #pragma unroll
    for (int nf = 0; nf < 4; nf++)
      #pragma unroll
      for (int r = 0; r < 4; r++)
        acc2[mf][nf][r] += bb2[nf];

  float S[4][4], Q[4][4];
  #pragma unroll
  for (int mf = 0; mf < 4; mf++) {
    #pragma unroll
    for (int r = 0; r < 4; r++) {
      float s = 0.f, q = 0.f;
      #pragma unroll
      for (int nf = 0; nf < 4; nf++) {
        float v = acc2[mf][nf][r];
        s += v; q += v * v;
      }
      S[mf][r] = s; Q[mf][r] = q;
    }
  }
  #pragma unroll
  for (int m = 1; m <= 8; m <<= 1) {
    #pragma unroll
    for (int mf = 0; mf < 4; mf++)
      #pragma unroll
      for (int r = 0; r < 4; r++) {
        S[mf][r] += __shfl_xor(S[mf][r], m);
        Q[mf][r] += __shfl_xor(Q[mf][r], m);
      }
  }
  if (llo == 0) {
    #pragma unroll
    for (int mf = 0; mf < 4; mf++)
      #pragma unroll
      for (int r = 0; r < 4; r++) {
        int row = mf * 16 + lhi * 4 + r;
        pS[wid * 64 + row] = S[mf][r];
        pQ[wid * 64 + row] = Q[mf][r];
      }
  }
  __syncthreads();  // also guarantees all GEMM2 hid reads complete

  float mu[4][4], rsv2[4][4];
  #pragma unroll
  for (int mf = 0; mf < 4; mf++) {
    #pragma unroll
    for (int r = 0; r < 4; r++) {
      int row = mf * 16 + lhi * 4 + r;
      float s = pS[row] + pS[64 + row] + pS[128 + row] + pS[192 + row];
      float q = pQ[row] + pQ[64 + row] + pQ[128 + row] + pQ[192 + row];
      float m_ = s * (1.f / 256.f);
      mu[mf][r]   = m_;
      rsv2[mf][r] = rsqrtf(q * (1.f / 256.f) - m_ * m_ + 1e-5f);
    }
  }

  // write final new_edge (LN + residual) into outt[64][260] f32 (overwrites hid)
  #pragma unroll
  for (int mf = 0; mf < 4; mf++) {
    #pragma unroll
    for (int r = 0; r < 4; r++) {
      int row = mf * 16 + lhi * 4 + r;
      #pragma unroll
      for (int nf = 0; nf < 4; nf++) {
        float v = (acc2[mf][nf][r] - mu[mf][r]) * rsv2[mf][r] * gg[nf] + be[nf]
                  + resv[mf][r][nf];
        outt[row * 260 + bcol2 + nf * 16] = v;
      }
    }
  }
  __syncthreads();

  // ---------------- store loop: full 1KB contiguous rows ----------------
  #pragma unroll
  for (int it = 0; it < 16; it++) {
    int row = it * 4 + wid;
    int e = eidx[row];
    f32x4 o4 = *((const f32x4*)(outt + row * 260) + lane);
    __builtin_nontemporal_store(o4, (f32x4*)(out + (size_t)e * 256) + lane);
  }
  __syncthreads();

  // ---------------- fused segment-sum over j (sorted within block) ----------------
  {
    int c = tid;  // column 0..255
    float acc = 0.f;
    int cj = idxj[0];
    #pragma unroll 8
    for (int r = 0; r < 64; r++) {
      int jr = idxj[r];
      if (jr != cj) {  // uniform branch
        atomicAdd(&aggf[(size_t)cj * 256 + c], acc);
        acc = 0.f; cj = jr;
      }
      acc += outt[r * 260 + c];
    }
    atomicAdd(&aggf[(size_t)cj * 256 + c], acc);
  }
}

// ---------------- node kernel (R15-proven M=64 structure; f32 agg input) ----------------
__global__ __launch_bounds__(256, 2)
void fused_node(const float* __restrict__ x,
                const short* __restrict__ xb,
                const float* __restrict__ aggf,
                const short* __restrict__ w1p,
                const float* __restrict__ b1,
                const short* __restrict__ w2p,
                const float* __restrict__ b2,
                const float* __restrict__ gam,
                const float* __restrict__ bet,
                float* __restrict__ out)
{
  constexpr int HP = 520;
  __shared__ __align__(16) short hid[64 * HP];
  __shared__ float pS[4][64], pQ[4][64];

  const int tid  = threadIdx.x;
  const int lane = tid & 63;
  const int wid  = tid >> 6;
  const int m0   = blockIdx.x * 64;
  const int lhi  = lane >> 4;
  const int llo  = lane & 15;

  const short* pI[4]; const float* pJ[4];
  #pragma unroll
  for (int mf = 0; mf < 4; mf++) {
    int rr = min(m0 + mf * 16 + llo, NNODE - 1);
    pI[mf] = xb + (size_t)rr * DD;
    pJ[mf] = aggf + (size_t)rr * DD;
  }

  f32x4 acc1[4][8] = {};
  const bf16x8* bp1 = (const bf16x8*)w1p;
  const int bcol1 = wid * 128 + llo;

  #pragma unroll
  for (int s = 0; s < 8; s++) {
    #pragma unroll
    for (int kk = 0; kk < 64; kk += 32) {
      const int ko = s * 64 + kk + lhi * 8;
      bf16x8 a[4];
      #pragma unroll
      for (int mf = 0; mf < 4; mf++) {
        if (s < 4) {
          a[mf] = *(const bf16x8*)(pI[mf] + ko);
        } else {
          const float* fp = pJ[mf] + (ko - 256);
          f32x4 u0 = *(const f32x4*)fp;
          f32x4 u1 = *(const f32x4*)(fp + 4);
          u32x4 q = { pkbf(u0.x, u0.y), pkbf(u0.z, u0.w),
                      pkbf(u1.x, u1.y), pkbf(u1.z, u1.w) };
          a[mf] = __builtin_bit_cast(bf16x8, q);
        }
      }
      const bf16x8* bb = bp1 + (size_t)(s * 8 + (kk >> 3) + lhi) * 512 + bcol1;
      #pragma unroll
      for (int nf = 0; nf < 8; nf++) {
        bf16x8 b = bb[nf * 16];
        #pragma unroll
        for (int mf = 0; mf < 4; mf++)
          acc1[mf][nf] = __builtin_amdgcn_mfma_f32_16x16x32_bf16(a[mf], b, acc1[mf][nf], 0, 0, 0);
      }
    }
  }

  #pragma unroll
  for (int nf = 0; nf < 8; nf++) {
    int col = wid * 128 + nf * 16 + llo;
    float bb = b1[col];
    #pragma unroll
    for (int mf = 0; mf < 4; mf++) {
      #pragma unroll
      for (int r = 0; r < 4; r++) {
        float v = acc1[mf][nf][r] + bb;
        v = v > 0.f ? v : 0.f;
        hid[(mf * 16 + lhi * 4 + r) * HP + col] = f2bf(v);
      }
    }
  }
  __syncthreads();

  f32x4 acc2[4][4] = {};
  const bf16x8* bp2 = (const bf16x8*)w2p;
  const int bcol2 = wid * 64 + llo;
  #pragma unroll
  for (int kk = 0; kk < 512; kk += 32) {
    bf16x8 a[4];
    #pragma unroll
    for (int mf = 0; mf < 4; mf++)
      a[mf] = *(const bf16x8*)(hid + (mf * 16 + llo) * HP + kk + lhi * 8);
    const bf16x8* bb = bp2 + (size_t)((kk >> 3) + lhi) * 256 + bcol2;
    #pragma unroll
    for (int nf = 0; nf < 4; nf++) {
      bf16x8 b = bb[nf * 16];
      #pragma unroll
      for (int mf = 0; mf < 4; mf++)
        acc2[mf][nf] = __builtin_amdgcn_mfma_f32_16x16x32_bf16(a[mf], b, acc2[mf][nf], 0, 0, 0);
    }
  }

  float bb2[4], gg[4], be[4];
  #pragma unroll
  for (int nf = 0; nf < 4; nf++) {
    int col = bcol2 + nf * 16;
    bb2[nf] = b2[col]; gg[nf] = gam[col]; be[nf] = bet[col];
  }
  #pragma unroll
  for (int mf = 0; mf < 4; mf++)
    #pragma unroll
    for (int nf = 0; nf < 4; nf++)
      #pragma unroll
      for (int r = 0; r < 4; r++)
        acc2[mf][nf][r] += bb2[nf];

  float S[4][4], Q[4][4];
  #pragma unroll
  for (int mf = 0; mf < 4; mf++) {
    #pragma unroll
    for (int r = 0; r < 4; r++) {
      float s = 0.f, q = 0.f;
      #pragma unroll
      for (int nf = 0; nf < 4; nf++) {
        float v = acc2[mf][nf][r];
        s += v; q += v * v;
      }
      S[mf][r] = s; Q[mf][r] = q;
    }
  }
  #pragma unroll
  for (int m = 1; m <= 8; m <<= 1) {
    #pragma unroll
    for (int mf = 0; mf < 4; mf++)
      #pragma unroll
      for (int r = 0; r < 4; r++) {
        S[mf][r] += __shfl_xor(S[mf][r], m);
        Q[mf][r] += __shfl_xor(Q[mf][r], m);
      }
  }
  if (llo == 0) {
    #pragma unroll
    for (int mf = 0; mf < 4; mf++)
      #pragma unroll
      for (int r = 0; r < 4; r++) {
        int row = mf * 16 + lhi * 4 + r;
        pS[wid][row] = S[mf][r];
        pQ[wid][row] = Q[mf][r];
      }
  }
  __syncthreads();

  float mu[4][4], rsv[4][4];
  #pragma unroll
  for (int mf = 0; mf < 4; mf++) {
    #pragma unroll
    for (int r = 0; r < 4; r++) {
      int row = mf * 16 + lhi * 4 + r;
      float s = pS[0][row] + pS[1][row] + pS[2][row] + pS[3][row];
      float q = pQ[0][row] + pQ[1][row] + pQ[2][row] + pQ[3][row];
      float m_ = s * (1.f / 256.f);
      mu[mf][r]  = m_;
      rsv[mf][r] = rsqrtf(q * (1.f / 256.f) - m_ * m_ + 1e-5f);
    }
  }

  #pragma unroll
  for (int mf = 0; mf < 4; mf++) {
    #pragma unroll
    for (int r = 0; r < 4; r++) {
      int grow = m0 + mf * 16 + lhi * 4 + r;
      if (grow >= NNODE) continue;
      const float* rp = x   + (size_t)grow * DD + bcol2;
      float*       op = out + (size_t)grow * DD + bcol2;
      #pragma unroll
      for (int nf = 0; nf < 4; nf++) {
        float v = (acc2[mf][nf][r] - mu[mf][r]) * rsv[mf][r] * gg[nf] + be[nf] + rp[nf * 16];
        op[nf * 16] = v;
      }
    }
  }
}

extern "C" void kernel_launch(void* const* d_in, const int* in_sizes, int n_in,
                              void* d_out, int out_size, void* d_ws, size_t ws_size,
                              hipStream_t stream) {
  const float* x      = (const float*)d_in[0];
  const int*   ei     = (const int*)  d_in[1];
  const float* ea     = (const float*)d_in[2];
  const float* e_w1   = (const float*)d_in[3];
  const float* e_b1   = (const float*)d_in[4];
  const float* e_w2   = (const float*)d_in[5];
  const float* e_b2   = (const float*)d_in[6];
  const float* e_g    = (const float*)d_in[7];
  const float* e_beta = (const float*)d_in[8];
  const float* n_w1   = (const float*)d_in[9];
  const float* n_b1   = (const float*)d_in[10];
  const float* n_w2   = (const float*)d_in[11];
  const float* n_b2   = (const float*)d_in[12];
  const float* n_g    = (const float*)d_in[13];
  const float* n_beta = (const float*)d_in[14];

  float* out_x = (float*)d_out;
  float* out_e = (float*)d_out + (size_t)NNODE * DD;

  char* w = (char*)d_ws;
  short* xb    = (short*)(w);                   //  5,120,000 B
  short* pab   = (short*)(w + 5120000);         // 20,480,000 B
  short* w1abp = (short*)(w + 25600000);        //    524,288 B
  short* w1cp  = (short*)(w + 26124288);        //    262,144 B
  short* ew2p  = (short*)(w + 26386432);        //    262,144 B
  short* nw1p  = (short*)(w + 26648576);        //    524,288 B
  short* nw2p  = (short*)(w + 27172864);        //    262,144 B
  float* aggf  = (float*)(w + 27435008);        // 10,240,000 B
  int*   deg   = (int*)  (w + 37675008);        //     40,960 B
  int*   cur   = (int*)  (w + 37715968);        //     40,960 B
  int*   rs    = (int*)  (w + 37756928);        //     40,976 B
  int*   csr   = (int*)  (w + 37797904);        //    640,000 B -> ~38.4 MB total

  hipMemsetAsync(deg, 0, 81920, stream);                          // deg + cursor
  hipMemsetAsync(aggf, 0, (size_t)NNODE * DD * sizeof(float), stream);

  cast_x_kernel<<<(NNODE * DD + 255) / 256, 256, 0, stream>>>(x, xb, NNODE * DD);
  pack_ew1_kernel<<<(768 * 512 + 255) / 256, 256, 0, stream>>>(e_w1, w1abp, w1cp);
  pack_w_kernel<<<(512 * 512 + 255) / 256, 256, 0, stream>>>(n_w1, nw1p, 512, 512);
  pack_w_kernel<<<(512 * 256 + 255) / 256, 256, 0, stream>>>(e_w2, ew2p, 512, 256);
  pack_w_kernel<<<(512 * 256 + 255) / 256, 256, 0, stream>>>(n_w2, nw2p, 512, 256);

  hist_kernel<<<(NEDGE + 255) / 256, 256, 0, stream>>>(ei, deg);
  scan_kernel<<<1, 256, 0, stream>>>(deg, rs);
  scatter_kernel<<<(NEDGE + 255) / 256, 256, 0, stream>>>(ei, rs, cur, csr);

  precomp_pab<<<dim3((NNODE + 63) / 64, 2), 256, 0, stream>>>(xb, w1abp, pab);

  fused_edge<<<NEDGE / 64, 256, 0, stream>>>(ei, csr, ea, pab, w1cp, e_b1,
                                             ew2p, e_b2, e_g, e_beta, out_e, aggf);
  fused_node<<<(NNODE + 63) / 64, 256, 0, stream>>>(x, xb, aggf, nw1p, n_b1,
                                                    nw2p, n_b2, n_g, n_beta, out_x);
}

// Round 19
// 434.452 us; speedup vs baseline: 1.1562x; 1.1562x over previous
//
#include <hip/hip_runtime.h>

#define NNODE 10000
#define NEDGE 160000
#define DD 256

using f32x4  = __attribute__((ext_vector_type(4))) float;
using bf16x8 = __attribute__((ext_vector_type(8))) short;
using u32x4  = __attribute__((ext_vector_type(4))) unsigned;

__device__ inline short f2bf(float f) {
  unsigned u = __float_as_uint(f);
  unsigned r = (u + 0x7fffu + ((u >> 16) & 1u)) >> 16;
  return (short)(unsigned short)r;
}

__device__ inline float bf2f(short s) {
  return __uint_as_float(((unsigned)(unsigned short)s) << 16);
}

__device__ inline unsigned pkbf(float a, float b) {
  unsigned r;
  asm("v_cvt_pk_bf16_f32 %0, %1, %2" : "=v"(r) : "v"(a), "v"(b));
  return r;
}

// bijective chunked XCD swizzle (8 XCDs) [m204]; measured neutral, kept (zero cost)
__device__ inline int xcd_chunked(int bid, int nwg) {
  const int NX = 8;
  int q = nwg / NX, r = nwg % NX;
  int x = bid % NX, pos = bid / NX;
  return (x < r) ? x * (q + 1) + pos : r * (q + 1) + (x - r) * q + pos;
}

__global__ void cast_x_kernel(const float* __restrict__ x, short* __restrict__ xb, int total) {
  int i = blockIdx.x * 256 + threadIdx.x;
  if (i < total) xb[i] = f2bf(x[i]);
}

// generic pack w[K][N] (f32) -> p[(k>>3)][n][k&7] (bf16)
__global__ void pack_w_kernel(const float* __restrict__ w, short* __restrict__ p, int K, int N) {
  int idx = blockIdx.x * 256 + threadIdx.x;
  if (idx >= K * N) return;
  int k = idx / N, n = idx - k * N;
  p[(size_t)(k >> 3) * N * 8 + (size_t)n * 8 + (k & 7)] = f2bf(w[idx]);
}

// e_w1 [768][512] split: rows 0..255 -> w1abp half0, 256..511 -> w1abp half1 (N=1024),
// rows 512..767 -> w1cp (N=512). Same MFMA-native (k>>3, n, k&7) layout.
__global__ void pack_ew1_kernel(const float* __restrict__ w, short* __restrict__ w1abp,
                                short* __restrict__ w1cp) {
  int idx = blockIdx.x * 256 + threadIdx.x;
  if (idx >= 768 * 512) return;
  int k = idx >> 9, n = idx & 511;
  short v = f2bf(w[idx]);
  if (k < 256) {
    w1abp[(size_t)(k >> 3) * 1024 * 8 + (size_t)n * 8 + (k & 7)] = v;
  } else if (k < 512) {
    int kk = k - 256;
    w1abp[(size_t)(kk >> 3) * 1024 * 8 + (size_t)(512 + n) * 8 + (kk & 7)] = v;
  } else {
    int kk = k - 512;
    w1cp[(size_t)(kk >> 3) * 512 * 8 + (size_t)n * 8 + (kk & 7)] = v;
  }
}

// ---------------- CSR build ----------------
__global__ void hist_kernel(const int* __restrict__ ei, int* __restrict__ deg) {
  int e = blockIdx.x * 256 + threadIdx.x;
  if (e < NEDGE) {
    int j = ei[NEDGE + e]; j = min(max(j, 0), NNODE - 1);
    atomicAdd(&deg[j], 1);
  }
}

__global__ void scan_kernel(const int* __restrict__ deg, int* __restrict__ row_start) {
  __shared__ int part[256];
  int t = threadIdx.x;
  const int CH = 40;
  int base = t * CH;
  int s = 0;
  for (int i = 0; i < CH; i++) {
    int idx = base + i;
    s += (idx < NNODE) ? deg[idx] : 0;
  }
  part[t] = s;
  __syncthreads();
  for (int off = 1; off < 256; off <<= 1) {
    int v = (t >= off) ? part[t - off] : 0;
    __syncthreads();
    part[t] += v;
    __syncthreads();
  }
  int run = (t == 0) ? 0 : part[t - 1];
  for (int i = 0; i < CH; i++) {
    int idx = base + i;
    if (idx < NNODE) { row_start[idx] = run; run += deg[idx]; }
  }
  if (t == 255) row_start[NNODE] = part[255];
}

__global__ void scatter_kernel(const int* __restrict__ ei, const int* __restrict__ row_start,
                               int* __restrict__ cursor, int* __restrict__ csr) {
  int e = blockIdx.x * 256 + threadIdx.x;
  if (e < NEDGE) {
    int j = ei[NEDGE + e]; j = min(max(j, 0), NNODE - 1);
    int p = atomicAdd(&cursor[j], 1);
    csr[row_start[j] + p] = e;
  }
}

// ---------------- precomp: Pab = x @ [W1a | W1b], packed-fragment bf16 ----------------
__global__ __launch_bounds__(256, 2)
void precomp_pab(const short* __restrict__ xb, const short* __restrict__ w1abp,
                 short* __restrict__ pab) {
  __shared__ __align__(16) short abuf[2048 * 8];  // 32 KB swizzled

  const int tid  = threadIdx.x;
  const int lane = tid & 63;
  const int wid  = tid >> 6;
  const int lhi  = lane >> 4;
  const int llo  = lane & 15;
  const int swz  = llo & 7;
  const int m0   = blockIdx.x * 64;
  const int h    = blockIdx.y;

  #pragma unroll
  for (int q = 0; q < 8; q++) {
    int S = wid * 512 + q * 64 + lane;
    int row = S >> 5;
    int segp = S & 31;
    int seg = segp ^ (row & 7);
    int rowg = min(m0 + row, NNODE - 1);
    __builtin_amdgcn_global_load_lds(
        (const int*)((const char*)xb + (size_t)rowg * 512 + seg * 16),
        (int*)(abuf + (size_t)(wid * 512 + q * 64) * 8), 16, 0, 0);
  }
  __syncthreads();

  f32x4 acc1[4][8] = {};
  const bf16x8* bp1 = (const bf16x8*)w1abp;
  #pragma unroll
  for (int kk = 0; kk < 256; kk += 32) {
    const int ks = kk >> 3;
    bf16x8 a[4];
    #pragma unroll
    for (int mf = 0; mf < 4; mf++)
      a[mf] = *(const bf16x8*)(abuf + ((mf * 16 + llo) * 32 + ((ks + lhi) ^ swz)) * 8);
    const bf16x8* bb = bp1 + (size_t)(ks + lhi) * 1024 + h * 512 + wid * 128 + llo;
    #pragma unroll
    for (int nf = 0; nf < 8; nf++) {
      bf16x8 b = bb[nf * 16];
      #pragma unroll
      for (int mf = 0; mf < 4; mf++)
        acc1[mf][nf] = __builtin_amdgcn_mfma_f32_16x16x32_bf16(a[mf], b, acc1[mf][nf], 0, 0, 0);
    }
  }

  #pragma unroll
  for (int mf = 0; mf < 4; mf++) {
    #pragma unroll
    for (int r = 0; r < 4; r++) {
      int row = m0 + mf * 16 + lhi * 4 + r;
      if (row < NNODE) {
        u32x4 wv = { pkbf(acc1[mf][0][r], acc1[mf][1][r]),
                     pkbf(acc1[mf][2][r], acc1[mf][3][r]),
                     pkbf(acc1[mf][4][r], acc1[mf][5][r]),
                     pkbf(acc1[mf][6][r], acc1[mf][7][r]) };
        *(u32x4*)(pab + (size_t)row * 1024 + h * 512 + llo * 32 + wid * 8) = wv;
      }
    }
  }
}

// ---------------- edge kernel (R17-proven: CSR-ordered, fused agg, pab[i] prefetch) ----------------
__global__ __launch_bounds__(256, 2)
void fused_edge(const int* __restrict__ ei,
                const int* __restrict__ csr,
                const float* __restrict__ ea,
                const short* __restrict__ pab,
                const short* __restrict__ w1cp,
                const float* __restrict__ b1,
                const short* __restrict__ w2p,
                const float* __restrict__ b2,
                const float* __restrict__ gam,
                const float* __restrict__ bet,
                float* __restrict__ out,
                float* __restrict__ aggf)
{
  // union region: abufE (32KB stage) -> hid (64KB bf16) -> outt (66.56KB f32)
  __shared__ __align__(16) char smem[66560];
  __shared__ int eidx[64], idxi[64], idxj[64];
  __shared__ float pS[256], pQ[256];

  short* abufE = (short*)smem;  // [64][32 segs of 8] bf16 (ea), swizzled
  short* hid   = (short*)smem;  // [64][512] bf16, XOR-swizzled
  float* outt  = (float*)smem;  // [64][260] f32

  const int tid  = threadIdx.x;
  const int lane = tid & 63;
  const int wid  = tid >> 6;
  const int lhi  = lane >> 4;
  const int llo  = lane & 15;
  const int swz  = llo & 7;
  const int m0   = xcd_chunked(blockIdx.x, gridDim.x) * 64;
  const int bcol2 = wid * 64 + llo;

  if (tid < 64) {
    int e = csr[m0 + tid];
    eidx[tid] = e;
    int a = ei[e];
    int b = ei[NEDGE + e];
    idxi[tid] = min(max(a, 0), NNODE - 1);
    idxj[tid] = min(max(b, 0), NNODE - 1);
  }
  __syncthreads();

  // stage ea tile (64 gathered rows, f32 -> bf16, swizzled); rows read ONCE -> nt
  #pragma unroll
  for (int q = 0; q < 8; q++) {
    int S = q * 256 + tid;
    int row = S >> 5;
    int segp = S & 31;
    int seg = segp ^ (row & 7);
    const f32x4* src = (const f32x4*)(ea + (size_t)eidx[row] * 256 + seg * 8);
    f32x4 u0 = __builtin_nontemporal_load(src);
    f32x4 u1 = __builtin_nontemporal_load(src + 1);
    u32x4 qv = { pkbf(u0.x, u0.y), pkbf(u0.z, u0.w), pkbf(u1.x, u1.y), pkbf(u1.z, u1.w) };
    *(u32x4*)(abufE + (size_t)S * 8) = qv;
  }
  __syncthreads();

  // PREFETCH pab[i] full rows into regs (16 independent 16B loads/thread); consumed
  // after GEMM_c so their L3 latency hides under the MFMA stream. [R16: -24us]
  // NOTE: pab[j] must NOT be prefetched early (R18: +67us — destroys the CSR-local
  // L2 reuse of shared j-lines); it stays as a late, L2-hot read below.
  bf16x8 paR[4][4];
  #pragma unroll
  for (int mf = 0; mf < 4; mf++) {
    #pragma unroll
    for (int r = 0; r < 4; r++) {
      int row = mf * 16 + lhi * 4 + r;
      paR[mf][r] = *(const bf16x8*)(pab + (size_t)idxi[row] * 1024 + llo * 32 + wid * 8);
    }
  }

  // ---------------- GEMM_c: [64 x 256] @ [256 x 512] ----------------
  f32x4 acc1[4][8] = {};
  const bf16x8* bp1 = (const bf16x8*)w1cp;
  #pragma unroll
  for (int kk = 0; kk < 256; kk += 32) {
    const int ks = kk >> 3;
    bf16x8 a[4];
    #pragma unroll
    for (int mf = 0; mf < 4; mf++)
      a[mf] = *(const bf16x8*)(abufE + ((mf * 16 + llo) * 32 + ((ks + lhi) ^ swz)) * 8);
    const bf16x8* bb = bp1 + (size_t)(ks + lhi) * 512 + wid * 128 + llo;
    #pragma unroll
    for (int nf = 0; nf < 8; nf++) {
      bf16x8 b = bb[nf * 16];
      #pragma unroll
      for (int mf = 0; mf < 4; mf++)
        acc1[mf][nf] = __builtin_amdgcn_mfma_f32_16x16x32_bf16(a[mf], b, acc1[mf][nf], 0, 0, 0);
    }
  }

  // add prefetched Pab[i] + gathered Pab[j] (CSR-local, L2-hot)
  #pragma unroll
  for (int mf = 0; mf < 4; mf++) {
    #pragma unroll
    for (int r = 0; r < 4; r++) {
      int row = mf * 16 + lhi * 4 + r;
      int gj = idxj[row];
      bf16x8 pb = *(const bf16x8*)(pab + (size_t)gj * 1024 + 512 + llo * 32 + wid * 8);
      #pragma unroll
      for (int nf = 0; nf < 8; nf++)
        acc1[mf][nf][r] += bf2f(paR[mf][r][nf]) + bf2f(pb[nf]);
    }
  }

  // snapshot this thread's residual (bf16 ea) from abufE before hid overwrites it
  float resv[4][4][4];
  #pragma unroll
  for (int mf = 0; mf < 4; mf++) {
    #pragma unroll
    for (int r = 0; r < 4; r++) {
      int row = mf * 16 + lhi * 4 + r;
      #pragma unroll
      for (int nf = 0; nf < 4; nf++) {
        int col = bcol2 + nf * 16;
        resv[mf][r][nf] = bf2f(abufE[row * 256 + (((col >> 3) ^ (row & 7)) << 3) + (col & 7)]);
      }
    }
  }
  __syncthreads();  // all abufE reads done before hid overwrites it

  // ---------------- bias + relu -> hid (XOR-swizzled, K=512) ----------------
  #pragma unroll
  for (int nf = 0; nf < 8; nf++) {
    int col = wid * 128 + nf * 16 + llo;
    float bb = b1[col];
    int cs = col >> 3, cl = col & 7;
    #pragma unroll
    for (int mf = 0; mf < 4; mf++) {
      #pragma unroll
      for (int r = 0; r < 4; r++) {
        int row = mf * 16 + lhi * 4 + r;
        float v = acc1[mf][nf][r] + bb;
        v = v > 0.f ? v : 0.f;
        hid[row * 512 + ((cs ^ (row & 7)) * 8) + cl] = f2bf(v);
      }
    }
  }
  __syncthreads();

  // ---------------- GEMM2: [64 x 512] @ [512 x 256] ----------------
  f32x4 acc2[4][4] = {};
  const bf16x8* bp2 = (const bf16x8*)w2p;
  #pragma unroll
  for (int kk = 0; kk < 512; kk += 32) {
    const int ks = kk >> 3;
    bf16x8 a[4];
    #pragma unroll
    for (int mf = 0; mf < 4; mf++) {
      int row = mf * 16 + llo;
      a[mf] = *(const bf16x8*)(hid + row * 512 + (((ks + lhi) ^ swz) * 8));
    }
    const bf16x8* bb = bp2 + (size_t)(ks + lhi) * 256 + bcol2;
    #pragma unroll
    for (int nf = 0; nf < 4; nf++) {
      bf16x8 b = bb[nf * 16];
      #pragma unroll
      for (int mf = 0; mf < 4; mf++)
        acc2[mf][nf] = __builtin_amdgcn_mfma_f32_16x16x32_bf16(a[mf], b, acc2[mf][nf], 0, 0, 0);
    }
  }

  // ---------------- LayerNorm stats ----------------
  float bb2[4], gg[4], be[4];
  #pragma unroll
  for (int nf = 0; nf < 4; nf++) {
    int col = bcol2 + nf * 16;
    bb2[nf] = b2[col]; gg[nf] = gam[col]; be[nf] = bet[col];
  }
  #pragma unroll
  for (int mf = 0; mf < 4; mf++)
    #pragma unroll
    for (int nf = 0; nf < 4; nf++)
      #pragma unroll
      for (int r = 0; r < 4; r++)
        acc2[mf][nf][r] += bb2[nf];

  float S[4][4], Q[4][4];
  #pragma unroll
  for (int mf = 0; mf < 4; mf++) {
    #pragma unroll
    for (int r = 0; r < 4; r++) {
      float s = 0.f, q = 0.f;
      #pragma unroll
      for (int nf = 0; nf < 4; nf++) {
        float v = acc2[mf][nf][r];
        s += v; q += v * v;
      }
      S[mf][r] = s; Q[mf][r] = q;
    }
  }
  #pragma unroll
  for (int m = 1; m <= 8; m <<= 1) {
    #pragma unroll
    for (int mf = 0; mf < 4; mf++)
      #pragma unroll
      for (int r = 0; r < 4; r++) {
        S[mf][r] += __shfl_xor(S[mf][r], m);
        Q[mf][r] += __shfl_xor(Q[mf][r], m);
      }
  }
  if (llo == 0) {
    #pragma unroll
    for (int mf = 0; mf < 4; mf++)
      #pragma unroll
      for (int r = 0; r < 4; r++) {
        int row = mf * 16 + lhi * 4 + r;
        pS[wid * 64 + row] = S[mf][r];
        pQ[wid * 64 + row] = Q[mf][r];
      }
  }
  __syncthreads();  // also guarantees all GEMM2 hid reads complete

  float mu[4][4], rsv2[4][4];
  #pragma unroll
  for (int mf = 0; mf < 4; mf++) {
    #pragma unroll
    for (int r = 0; r < 4; r++) {
      int row = mf * 16 + lhi * 4 + r;
      float s = pS[row] + pS[64 + row] + pS[128 + row] + pS[192 + row];
      float q = pQ[row] + pQ[64 + row] + pQ[128 + row] + pQ[192 + row];
      float m_ = s * (1.f / 256.f);
      mu[mf][r]   = m_;
      rsv2[mf][r] = rsqrtf(q * (1.f / 256.f) - m_ * m_ + 1e-5f);
    }
  }

  // write final new_edge (LN + residual) into outt[64][260] f32 (overwrites hid)
  #pragma unroll
  for (int mf = 0; mf < 4; mf++) {
    #pragma unroll
    for (int r = 0; r < 4; r++) {
      int row = mf * 16 + lhi * 4 + r;
      #pragma unroll
      for (int nf = 0; nf < 4; nf++) {
        float v = (acc2[mf][nf][r] - mu[mf][r]) * rsv2[mf][r] * gg[nf] + be[nf]
                  + resv[mf][r][nf];
        outt[row * 260 + bcol2 + nf * 16] = v;
      }
    }
  }
  __syncthreads();

  // ---------------- store loop: full 1KB contiguous rows ----------------
  #pragma unroll
  for (int it = 0; it < 16; it++) {
    int row = it * 4 + wid;
    int e = eidx[row];
    f32x4 o4 = *((const f32x4*)(outt + row * 260) + lane);
    __builtin_nontemporal_store(o4, (f32x4*)(out + (size_t)e * 256) + lane);
  }
  __syncthreads();

  // ---------------- fused segment-sum over j (sorted within block) ----------------
  {
    int c = tid;  // column 0..255
    float acc = 0.f;
    int cj = idxj[0];
    #pragma unroll 8
    for (int r = 0; r < 64; r++) {
      int jr = idxj[r];
      if (jr != cj) {  // uniform branch
        atomicAdd(&aggf[(size_t)cj * 256 + c], acc);
        acc = 0.f; cj = jr;
      }
      acc += outt[r * 260 + c];
    }
    atomicAdd(&aggf[(size_t)cj * 256 + c], acc);
  }
}

// ---------------- node kernel (R15-proven M=64 structure; f32 agg input) ----------------
__global__ __launch_bounds__(256, 2)
void fused_node(const float* __restrict__ x,
                const short* __restrict__ xb,
                const float* __restrict__ aggf,
                const short* __restrict__ w1p,
                const float* __restrict__ b1,
                const short* __restrict__ w2p,
                const float* __restrict__ b2,
                const float* __restrict__ gam,
                const float* __restrict__ bet,
                float* __restrict__ out)
{
  constexpr int HP = 520;
  __shared__ __align__(16) short hid[64 * HP];
  __shared__ float pS[4][64], pQ[4][64];

  const int tid  = threadIdx.x;
  const int lane = tid & 63;
  const int wid  = tid >> 6;
  const int m0   = blockIdx.x * 64;
  const int lhi  = lane >> 4;
  const int llo  = lane & 15;

  const short* pI[4]; const float* pJ[4];
  #pragma unroll
  for (int mf = 0; mf < 4; mf++) {
    int rr = min(m0 + mf * 16 + llo, NNODE - 1);
    pI[mf] = xb + (size_t)rr * DD;
    pJ[mf] = aggf + (size_t)rr * DD;
  }

  f32x4 acc1[4][8] = {};
  const bf16x8* bp1 = (const bf16x8*)w1p;
  const int bcol1 = wid * 128 + llo;

  #pragma unroll
  for (int s = 0; s < 8; s++) {
    #pragma unroll
    for (int kk = 0; kk < 64; kk += 32) {
      const int ko = s * 64 + kk + lhi * 8;
      bf16x8 a[4];
      #pragma unroll
      for (int mf = 0; mf < 4; mf++) {
        if (s < 4) {
          a[mf] = *(const bf16x8*)(pI[mf] + ko);
        } else {
          const float* fp = pJ[mf] + (ko - 256);
          f32x4 u0 = *(const f32x4*)fp;
          f32x4 u1 = *(const f32x4*)(fp + 4);
          u32x4 q = { pkbf(u0.x, u0.y), pkbf(u0.z, u0.w),
                      pkbf(u1.x, u1.y), pkbf(u1.z, u1.w) };
          a[mf] = __builtin_bit_cast(bf16x8, q);
        }
      }
      const bf16x8* bb = bp1 + (size_t)(s * 8 + (kk >> 3) + lhi) * 512 + bcol1;
      #pragma unroll
      for (int nf = 0; nf < 8; nf++) {
        bf16x8 b = bb[nf * 16];
        #pragma unroll
        for (int mf = 0; mf < 4; mf++)
          acc1[mf][nf] = __builtin_amdgcn_mfma_f32_16x16x32_bf16(a[mf], b, acc1[mf][nf], 0, 0, 0);
      }
    }
  }

  #pragma unroll
  for (int nf = 0; nf < 8; nf++) {
    int col = wid * 128 + nf * 16 + llo;
    float bb = b1[col];
    #pragma unroll
    for (int mf = 0; mf < 4; mf++) {
      #pragma unroll
      for (int r = 0; r < 4; r++) {
        float v = acc1[mf][nf][r] + bb;
        v = v > 0.f ? v : 0.f;
        hid[(mf * 16 + lhi * 4 + r) * HP + col] = f2bf(v);
      }
    }
  }
  __syncthreads();

  f32x4 acc2[4][4] = {};
  const bf16x8* bp2 = (const bf16x8*)w2p;
  const int bcol2 = wid * 64 + llo;
  #pragma unroll
  for (int kk = 0; kk < 512; kk += 32) {
    bf16x8 a[4];
    #pragma unroll
    for (int mf = 0; mf < 4; mf++)
      a[mf] = *(const bf16x8*)(hid + (mf * 16 + llo) * HP + kk + lhi * 8);
    const bf16x8* bb = bp2 + (size_t)((kk >> 3) + lhi) * 256 + bcol2;
    #pragma unroll
    for (int nf = 0; nf < 4; nf++) {
      bf16x8 b = bb[nf * 16];
      #pragma unroll
      for (int mf = 0; mf < 4; mf++)
        acc2[mf][nf] = __builtin_amdgcn_mfma_f32_16x16x32_bf16(a[mf], b, acc2[mf][nf], 0, 0, 0);
    }
  }

  float bb2[4], gg[4], be[4];
  #pragma unroll
  for (int nf = 0; nf < 4; nf++) {
    int col = bcol2 + nf * 16;
    bb2[nf] = b2[col]; gg[nf] = gam[col]; be[nf] = bet[col];
  }
  #pragma unroll
  for (int mf = 0; mf < 4; mf++)
    #pragma unroll
    for (int nf = 0; nf < 4; nf++)
      #pragma unroll
      for (int r = 0; r < 4; r++)
        acc2[mf][nf][r] += bb2[nf];

  float S[4][4], Q[4][4];
  #pragma unroll
  for (int mf = 0; mf < 4; mf++) {
    #pragma unroll
    for (int r = 0; r < 4; r++) {
      float s = 0.f, q = 0.f;
      #pragma unroll
      for (int nf = 0; nf < 4; nf++) {
        float v = acc2[mf][nf][r];
        s += v; q += v * v;
      }
      S[mf][r] = s; Q[mf][r] = q;
    }
  }
  #pragma unroll
  for (int m = 1; m <= 8; m <<= 1) {
    #pragma unroll
    for (int mf = 0; mf < 4; mf++)
      #pragma unroll
      for (int r = 0; r < 4; r++) {
        S[mf][r] += __shfl_xor(S[mf][r], m);
        Q[mf][r] += __shfl_xor(Q[mf][r], m);
      }
  }
  if (llo == 0) {
    #pragma unroll
    for (int mf = 0; mf < 4; mf++)
      #pragma unroll
      for (int r = 0; r < 4; r++) {
        int row = mf * 16 + lhi * 4 + r;
        pS[wid][row] = S[mf][r];
        pQ[wid][row] = Q[mf][r];
      }
  }
  __syncthreads();

  float mu[4][4], rsv[4][4];
  #pragma unroll
  for (int mf = 0; mf < 4; mf++) {
    #pragma unroll
    for (int r = 0; r < 4; r++) {
      int row = mf * 16 + lhi * 4 + r;
      float s = pS[0][row] + pS[1][row] + pS[2][row] + pS[3][row];
      float q = pQ[0][row] + pQ[1][row] + pQ[2][row] + pQ[3][row];
      float m_ = s * (1.f / 256.f);
      mu[mf][r]  = m_;
      rsv[mf][r] = rsqrtf(q * (1.f / 256.f) - m_ * m_ + 1e-5f);
    }
  }

  #pragma unroll
  for (int mf = 0; mf < 4; mf++) {
    #pragma unroll
    for (int r = 0; r < 4; r++) {
      int grow = m0 + mf * 16 + lhi * 4 + r;
      if (grow >= NNODE) continue;
      const float* rp = x   + (size_t)grow * DD + bcol2;
      float*       op = out + (size_t)grow * DD + bcol2;
      #pragma unroll
      for (int nf = 0; nf < 4; nf++) {
        float v = (acc2[mf][nf][r] - mu[mf][r]) * rsv[mf][r] * gg[nf] + be[nf] + rp[nf * 16];
        op[nf * 16] = v;
      }
    }
  }
}

extern "C" void kernel_launch(void* const* d_in, const int* in_sizes, int n_in,
                              void* d_out, int out_size, void* d_ws, size_t ws_size,
                              hipStream_t stream) {
  const float* x      = (const float*)d_in[0];
  const int*   ei     = (const int*)  d_in[1];
  const float* ea     = (const float*)d_in[2];
  const float* e_w1   = (const float*)d_in[3];
  const float* e_b1   = (const float*)d_in[4];
  const float* e_w2   = (const float*)d_in[5];
  const float* e_b2   = (const float*)d_in[6];
  const float* e_g    = (const float*)d_in[7];
  const float* e_beta = (const float*)d_in[8];
  const float* n_w1   = (const float*)d_in[9];
  const float* n_b1   = (const float*)d_in[10];
  const float* n_w2   = (const float*)d_in[11];
  const float* n_b2   = (const float*)d_in[12];
  const float* n_g    = (const float*)d_in[13];
  const float* n_beta = (const float*)d_in[14];

  float* out_x = (float*)d_out;
  float* out_e = (float*)d_out + (size_t)NNODE * DD;

  char* w = (char*)d_ws;
  short* xb    = (short*)(w);                   //  5,120,000 B
  short* pab   = (short*)(w + 5120000);         // 20,480,000 B
  short* w1abp = (short*)(w + 25600000);        //    524,288 B
  short* w1cp  = (short*)(w + 26124288);        //    262,144 B
  short* ew2p  = (short*)(w + 26386432);        //    262,144 B
  short* nw1p  = (short*)(w + 26648576);        //    524,288 B
  short* nw2p  = (short*)(w + 27172864);        //    262,144 B
  float* aggf  = (float*)(w + 27435008);        // 10,240,000 B
  int*   deg   = (int*)  (w + 37675008);        //     40,960 B
  int*   cur   = (int*)  (w + 37715968);        //     40,960 B
  int*   rs    = (int*)  (w + 37756928);        //     40,976 B
  int*   csr   = (int*)  (w + 37797904);        //    640,000 B -> ~38.4 MB total

  hipMemsetAsync(deg, 0, 81920, stream);                          // deg + cursor
  hipMemsetAsync(aggf, 0, (size_t)NNODE * DD * sizeof(float), stream);

  cast_x_kernel<<<(NNODE * DD + 255) / 256, 256, 0, stream>>>(x, xb, NNODE * DD);
  pack_ew1_kernel<<<(768 * 512 + 255) / 256, 256, 0, stream>>>(e_w1, w1abp, w1cp);
  pack_w_kernel<<<(512 * 512 + 255) / 256, 256, 0, stream>>>(n_w1, nw1p, 512, 512);
  pack_w_kernel<<<(512 * 256 + 255) / 256, 256, 0, stream>>>(e_w2, ew2p, 512, 256);
  pack_w_kernel<<<(512 * 256 + 255) / 256, 256, 0, stream>>>(n_w2, nw2p, 512, 256);

  hist_kernel<<<(NEDGE + 255) / 256, 256, 0, stream>>>(ei, deg);
  scan_kernel<<<1, 256, 0, stream>>>(deg, rs);
  scatter_kernel<<<(NEDGE + 255) / 256, 256, 0, stream>>>(ei, rs, cur, csr);

  precomp_pab<<<dim3((NNODE + 63) / 64, 2), 256, 0, stream>>>(xb, w1abp, pab);

  fused_edge<<<NEDGE / 64, 256, 0, stream>>>(ei, csr, ea, pab, w1cp, e_b1,
                                             ew2p, e_b2, e_g, e_beta, out_e, aggf);
  fused_node<<<(NNODE + 63) / 64, 256, 0, stream>>>(x, xb, aggf, nw1p, n_b1,
                                                    nw2p, n_b2, n_g, n_beta, out_x);
}